// Round 2
// baseline (384.595 us; speedup 1.0000x reference)
//
#include <hip/hip_runtime.h>
#include <math.h>

#define B     32
#define CIN   128
#define NN    8192
#define N1    8190     // output length after k=3 valid conv
#define CH    10
#define TOUT  252      // diag outputs per block (h2 tile = TOUT+4 = 256 cols)
#define NTILE 33       // ceil(8190/252)

// K0: transpose w1[o][ci][k] -> wT[ci][o*3+k] (rows padded to 32 floats)
// so k_main's per-channel 30 weights are contiguous wave-uniform s_loads.
__global__ void k0_prep(const float* __restrict__ w1, float* __restrict__ wT)
{
    const int i = blockIdx.x * 256 + threadIdx.x;     // 0..4095
    if (i < CIN * 32) {
        const int ci = i >> 5, r = i & 31;
        float v = 0.f;
        if (r < 30) {
            const int o = r / 3, k = r - o * 3;
            v = w1[(o * CIN + ci) * 3 + k];
        }
        wT[i] = v;
    }
}

// K_MAIN: whole pipeline per 252-output tile, 512 threads = 2 channel-groups.
// Phase 1: each group streams 64 input channels with the round-0 simple
//   chunk loop (compiler's own schedule — the R1 sched_barrier pipeline
//   regressed 89->120us, so it is reverted). Group 1 writes partial
//   pre-activation sums to LDS; group 0 adds them (reduction BEFORE relu).
//   This halves the per-wave serialized load->FMA path and doubles
//   waves/SIMD (4.1 -> 8.25) — both attack the measured latency-bound
//   regime (dur identical at 892 GB/s and 12 GB/s HBM).
// Phase 2 (group 0 only): convT(k=3)+relu+1x1+sigmoid -> lr; tridiag+log.
__global__ __launch_bounds__(512, 4) void k_main(
    const float* __restrict__ sig, const float* __restrict__ wT,
    const float* __restrict__ b1, const float* __restrict__ w2, const float* __restrict__ b2,
    const float* __restrict__ wt, const float* __restrict__ bt,
    const float* __restrict__ w3, const float* __restrict__ b3,
    const float* __restrict__ cd, const float* __restrict__ cstp,
    float* __restrict__ outv, float* __restrict__ bsums)
{
    __shared__ float ypart[CH * 256];  // 10240 B  group-1 partial conv1 sums
    __shared__ float h2s[CH * 256];    // 10240 B  [o][col]
    __shared__ float lsh[256], rsh[256];
    __shared__ float red[8];

    const int tid = threadIdx.x;
    const int grp = tid >> 8;                         // 0 or 1 (64-ch group)
    const int lid = tid & 255;                        // column lane within group
    const int b   = blockIdx.y;
    const int t0  = blockIdx.x * TOUT;
    const int g   = t0 - 2 + lid;                     // h2 column of this thread
    const bool gvalid = (g >= 0) && (g < N1);
    const bool sh = (g > NN - 4);                     // only g==8189 among valid cols
    int gl = (g < 0) ? 0 : g;
    if (gl > NN - 4) gl = NN - 4;                     // float4 [gl..gl+3] always in-bounds
    const float* __restrict__ sb =
        sig + (size_t)b * CIN * NN + (size_t)grp * 64 * NN + gl;

    float y[CH];
#pragma unroll
    for (int o = 0; o < CH; ++o) y[o] = grp ? 0.f : b1[o];

    // ---- Phase 1: 4 chunks x 16 channels (this group's 64 channels) ----
    for (int c = 0; c < 4; ++c) {
        float4 v[16];
#pragma unroll
        for (int j = 0; j < 16; ++j)
            v[j] = *(const float4*)(sb + (size_t)(c * 16 + j) * NN);

        const float* wbase = wT + (grp * 64 + c * 16) * 32;
#pragma unroll
        for (int j = 0; j < 16; ++j) {
            const float s0 = sh ? v[j].y : v[j].x;    // signal[g]
            const float s1 = sh ? v[j].z : v[j].y;    // signal[g+1]
            const float s2 = sh ? v[j].w : v[j].z;    // signal[g+2]
            const float* wrow = wbase + j * 32;       // 30 contiguous uniform weights
#pragma unroll
            for (int o = 0; o < CH; ++o) {
                y[o] = fmaf(wrow[o * 3 + 0], s0, y[o]);
                y[o] = fmaf(wrow[o * 3 + 1], s1, y[o]);
                y[o] = fmaf(wrow[o * 3 + 2], s2, y[o]);
            }
        }
    }

    // cross-group reduction of pre-activation sums (must precede relu)
    if (grp == 1) {
#pragma unroll
        for (int o = 0; o < CH; ++o) ypart[o * 256 + lid] = y[o];
    }
    __syncthreads();

    if (grp == 0) {
        // conv2 (1x1) + relu -> LDS (zero outside [0,N1) for convT zero-pad)
#pragma unroll
        for (int o = 0; o < CH; ++o)
            y[o] = fmaxf(y[o] + ypart[o * 256 + lid], 0.f);
#pragma unroll
        for (int o = 0; o < CH; ++o) {
            float a = b2[o];
#pragma unroll
            for (int i = 0; i < CH; ++i) a = fmaf(w2[o * CH + i], y[i], a);
            h2s[o * 256 + lid] = gvalid ? fmaxf(a, 0.f) : 0.f;
        }
    }
    __syncthreads();

    // convT + relu + 1x1 + sigmoid -> lr at s = t0 + tid (tid < 254 => grp 0)
    const int s = t0 + tid;
    if (tid < 254 && s < NN) {
        float acc[CH];
#pragma unroll
        for (int o = 0; o < CH; ++o) acc[o] = bt[o];
#pragma unroll
        for (int i = 0; i < CH; ++i) {
            const float a0 = h2s[i * 256 + tid];      // h2[s-2]
            const float a1 = h2s[i * 256 + tid + 1];  // h2[s-1]
            const float a2 = h2s[i * 256 + tid + 2];  // h2[s]
            const float* wp = wt + i * CH * 3;        // contiguous uniform
#pragma unroll
            for (int o = 0; o < CH; ++o) {
                acc[o] = fmaf(wp[o * 3 + 0], a2, acc[o]);
                acc[o] = fmaf(wp[o * 3 + 1], a1, acc[o]);
                acc[o] = fmaf(wp[o * 3 + 2], a0, acc[o]);
            }
        }
        float l = b3[0], r = b3[1];
#pragma unroll
        for (int o = 0; o < CH; ++o) {
            const float h3 = fmaxf(acc[o], 0.f);
            l = fmaf(w3[o],      h3, l);
            r = fmaf(w3[CH + o], h3, r);
        }
        lsh[tid] = 1.f / (1.f + __expf(-l));
        rsh[tid] = 1.f / (1.f + __expf(-r));
    }
    __syncthreads();

    // tridiagonal update + log for t = t0 + tid (tid < TOUT => grp 0)
    float vlog = 0.f;
    const int t = t0 + tid;
    if (tid < TOUT && t < N1) {
        const float c0 = cd[(size_t)b * (NN - 1) + t];
        const float c1 = cd[(size_t)b * (NN - 1) + t + 1];
        const float mi = c1 * rsh[tid + 1] + c0 * lsh[tid + 1];
        const float mo = rsh[tid] + lsh[tid + 2];
        vlog = __logf(cstp[0] * mi / mo);
        outv[(size_t)b * N1 + t] = vlog;
    }

    // block sum: wave shuffle reduce, then 8 partials through LDS
    float vs = vlog;
#pragma unroll
    for (int off = 32; off > 0; off >>= 1) vs += __shfl_down(vs, off);
    if ((tid & 63) == 0) red[tid >> 6] = vs;
    __syncthreads();
    if (tid == 0) {
        float sgrand = 0.f;
#pragma unroll
        for (int k = 0; k < 8; ++k) sgrand += red[k];
        bsums[blockIdx.y * NTILE + blockIdx.x] = sgrand;
    }
}

// K3: every block redundantly reduces the 1056 bsums (L2-hot), subtracts mean.
__global__ __launch_bounds__(256) void k3_meansub(
    const float* __restrict__ bsums, float* __restrict__ outv, int n)
{
    __shared__ float red[256];
    const int tid = threadIdx.x;
    float s = 0.f;
    for (int i = tid; i < NTILE * B; i += 256) s += bsums[i];
    red[tid] = s;
    __syncthreads();
#pragma unroll
    for (int st = 128; st > 0; st >>= 1) {
        if (tid < st) red[tid] += red[tid + st];
        __syncthreads();
    }
    const float mean = red[0] / (float)(B * N1);
    __syncthreads();
    const int i = blockIdx.x * 256 + tid;
    if (i < n) outv[i] -= mean;
}

extern "C" void kernel_launch(void* const* d_in, const int* in_sizes, int n_in,
                              void* d_out, int out_size, void* d_ws, size_t ws_size,
                              hipStream_t stream)
{
    const float* sig = (const float*)d_in[0];
    const float* cd  = (const float*)d_in[1];
    // d_in[2] = index_diag (1 for these shapes)
    const float* w1  = (const float*)d_in[3];
    const float* b1  = (const float*)d_in[4];
    const float* w2  = (const float*)d_in[5];
    const float* b2  = (const float*)d_in[6];
    const float* wt  = (const float*)d_in[7];
    const float* bt  = (const float*)d_in[8];
    const float* w3  = (const float*)d_in[9];
    const float* b3  = (const float*)d_in[10];
    const float* cst = (const float*)d_in[11];

    float* outv = (float*)d_out;

    // workspace layout (floats)
    float* ws   = (float*)d_ws;
    float* wT   = ws;                  // CIN*32 = 4096
    float* bsum = wT + CIN * 32;       // NTILE*B = 1056

    k0_prep   <<<dim3(16), dim3(256), 0, stream>>>(w1, wT);
    k_main    <<<dim3(NTILE, B), dim3(512), 0, stream>>>(sig, wT, b1, w2, b2,
                                                         wt, bt, w3, b3, cd, cst, outv, bsum);
    k3_meansub<<<dim3((out_size + 255) / 256), dim3(256), 0, stream>>>(bsum, outv, out_size);
}

// Round 3
// 239.636 us; speedup vs baseline: 1.6049x; 1.6049x over previous
//
#include <hip/hip_runtime.h>
#include <math.h>

#define B     32
#define CIN   128
#define NN    8192
#define N1    8190     // output length after k=3 valid conv
#define CH    10
#define TOUT  252      // diag outputs per block (h2 tile = TOUT+4 = 256 cols)
#define NTILE 33       // ceil(8190/252)
#define COLS  264      // staged cols per channel: [t0-4, t0+259], 66 float4
#define CPC   8        // channels per chunk
#define NCHK  16       // chunks

// K0: transpose w1[o][ci][k] -> wT[ci][o*3+k] (rows padded to 32 floats)
// so k_main's per-channel 30 weights are contiguous wave-uniform s_loads.
__global__ void k0_prep(const float* __restrict__ w1, float* __restrict__ wT)
{
    const int i = blockIdx.x * 256 + threadIdx.x;     // 0..4095
    if (i < CIN * 32) {
        const int ci = i >> 5, r = i & 31;
        float v = 0.f;
        if (r < 30) {
            const int o = r / 3, k = r - o * 3;
            v = w1[(o * CIN + ci) * 3 + k];
        }
        wT[i] = v;
    }
}

typedef __attribute__((address_space(1))) void g_void;
typedef __attribute__((address_space(3))) void l_void;

__device__ __forceinline__ void gld16(const float* g, float* l)
{
    // async global->LDS, 16B per lane; LDS dest = wave-uniform base + lane*16
    __builtin_amdgcn_global_load_lds((g_void*)g, (l_void*)l, 16, 0, 0);
}

// Stage chunk c (8 channels x 264 cols = 528 float4, LDS-contiguous) into buf.
// i-th float4 -> buf bytes [16i,16i+16): linear dest matches the wave pattern.
// Clamped float4s only cover columns masked by gvalid later (verified edges).
__device__ __forceinline__ void stage_chunk(const float* __restrict__ sigb, int c,
                                            float* buf, int tid, int scol0)
{
    const float* rowbase = sigb + (size_t)(c * CPC) * NN;
#pragma unroll
    for (int k = 0; k < 2; ++k) {
        const int i = k * 256 + tid;
        const int row = (int)((unsigned)i / 66u);
        int col = scol0 + (i - row * 66) * 4;
        col = col < 0 ? 0 : (col > NN - 4 ? NN - 4 : col);
        gld16(rowbase + (size_t)row * NN + col, buf + i * 4);
    }
    if (tid < 16) {                                   // 528 = 2*256 + 16
        const int i = 512 + tid;                      // row 7, offs 50..65
        int col = scol0 + (i - 462) * 4;
        col = col > NN - 4 ? NN - 4 : col;
        gld16(rowbase + (size_t)7 * NN + col, buf + i * 4);
    }
}

// K_MAIN: whole pipeline per 252-output tile, 256 threads.
// Phase 1: conv1 via double-buffered global_load_lds staging — replaces the
//   per-thread serial float4 chain (R0-R2: VGPR 40/64/36 proved hipcc always
//   sinks reg batches -> latency-bound at 89-227us). Coalesced 1x staging,
//   ~2 VMEM issues/thread/chunk, drained by the chunk barrier after ~600cy
//   of FMA (m97 pattern). Weight addressing block-uniform again -> s_loads.
// Phase 2 (LDS): convT(k=3)+relu+1x1+sigmoid -> lr; tridiag+log; block sum.
__global__ __launch_bounds__(256, 4) void k_main(
    const float* __restrict__ sig, const float* __restrict__ wT,
    const float* __restrict__ b1, const float* __restrict__ w2, const float* __restrict__ b2,
    const float* __restrict__ wt, const float* __restrict__ bt,
    const float* __restrict__ w3, const float* __restrict__ b3,
    const float* __restrict__ cd, const float* __restrict__ cstp,
    float* __restrict__ outv, float* __restrict__ bsums)
{
    __shared__ float bufA[CPC * COLS];   // 8448 B
    __shared__ float bufB[CPC * COLS];   // 8448 B
    __shared__ float h2s[CH * 256];      // 10240 B  [o][col]
    __shared__ float lsh[256], rsh[256];
    __shared__ float red[4];

    const int tid = threadIdx.x;
    const int b   = blockIdx.y;
    const int t0  = blockIdx.x * TOUT;
    const int scol0 = t0 - 4;                         // 16B-aligned (252bx%4==0)
    const int g   = t0 - 2 + tid;                     // h2 column of this thread
    const bool gvalid = (g >= 0) && (g < N1);
    const float* __restrict__ sigb = sig + (size_t)b * CIN * NN;

    float y[CH];
#pragma unroll
    for (int o = 0; o < CH; ++o) y[o] = b1[o];

    // ---- Phase 1: 16 chunks x 8 channels, double-buffered LDS staging ----
    stage_chunk(sigb, 0, bufA, tid, scol0);
    __syncthreads();                                  // drains vmcnt

    for (int c = 0; c < NCHK; ++c) {
        float* cur = (c & 1) ? bufB : bufA;
        float* nxt = (c & 1) ? bufA : bufB;
        if (c < NCHK - 1) stage_chunk(sigb, c + 1, nxt, tid, scol0);

        const float* bl = cur + tid + 2;              // idx tid+2 <=> col g
#pragma unroll
        for (int j = 0; j < CPC; ++j) {
            const float s0 = bl[j * COLS + 0];        // sig[ch][g]
            const float s1 = bl[j * COLS + 1];        // sig[ch][g+1]
            const float s2 = bl[j * COLS + 2];        // sig[ch][g+2]
            const float* wrow = wT + (c * CPC + j) * 32;
#pragma unroll
            for (int o = 0; o < CH; ++o) {
                y[o] = fmaf(wrow[o * 3 + 0], s0, y[o]);
                y[o] = fmaf(wrow[o * 3 + 1], s1, y[o]);
                y[o] = fmaf(wrow[o * 3 + 2], s2, y[o]);
            }
        }
        __syncthreads();                              // readers done + prefetch drained
    }

    // conv2 (1x1) + relu -> LDS (zero outside [0,N1) for convT zero-padding)
#pragma unroll
    for (int o = 0; o < CH; ++o) y[o] = fmaxf(y[o], 0.f);
#pragma unroll
    for (int o = 0; o < CH; ++o) {
        float a = b2[o];
#pragma unroll
        for (int i = 0; i < CH; ++i) a = fmaf(w2[o * CH + i], y[i], a);
        h2s[o * 256 + tid] = gvalid ? fmaxf(a, 0.f) : 0.f;
    }
    __syncthreads();

    // convT + relu + 1x1 + sigmoid -> lr at s = t0 + tid (tid < 254)
    const int s = t0 + tid;
    if (tid < 254 && s < NN) {
        float acc[CH];
#pragma unroll
        for (int o = 0; o < CH; ++o) acc[o] = bt[o];
#pragma unroll
        for (int i = 0; i < CH; ++i) {
            const float a0 = h2s[i * 256 + tid];      // h2[s-2]
            const float a1 = h2s[i * 256 + tid + 1];  // h2[s-1]
            const float a2 = h2s[i * 256 + tid + 2];  // h2[s]
            const float* wp = wt + i * CH * 3;        // contiguous uniform
#pragma unroll
            for (int o = 0; o < CH; ++o) {
                acc[o] = fmaf(wp[o * 3 + 0], a2, acc[o]);
                acc[o] = fmaf(wp[o * 3 + 1], a1, acc[o]);
                acc[o] = fmaf(wp[o * 3 + 2], a0, acc[o]);
            }
        }
        float l = b3[0], r = b3[1];
#pragma unroll
        for (int o = 0; o < CH; ++o) {
            const float h3 = fmaxf(acc[o], 0.f);
            l = fmaf(w3[o],      h3, l);
            r = fmaf(w3[CH + o], h3, r);
        }
        lsh[tid] = 1.f / (1.f + __expf(-l));
        rsh[tid] = 1.f / (1.f + __expf(-r));
    }
    __syncthreads();

    // tridiagonal update + log for t = t0 + tid (tid < TOUT)
    float vlog = 0.f;
    const int t = t0 + tid;
    if (tid < TOUT && t < N1) {
        const float c0 = cd[(size_t)b * (NN - 1) + t];
        const float c1 = cd[(size_t)b * (NN - 1) + t + 1];
        const float mi = c1 * rsh[tid + 1] + c0 * lsh[tid + 1];
        const float mo = rsh[tid] + lsh[tid + 2];
        vlog = __logf(cstp[0] * mi / mo);
        outv[(size_t)b * N1 + t] = vlog;
    }

    // block sum: wave shuffle reduce, then 4 partials through LDS
    float vs = vlog;
#pragma unroll
    for (int off = 32; off > 0; off >>= 1) vs += __shfl_down(vs, off);
    if ((tid & 63) == 0) red[tid >> 6] = vs;
    __syncthreads();
    if (tid == 0)
        bsums[blockIdx.y * NTILE + blockIdx.x] = red[0] + red[1] + red[2] + red[3];
}

// K3: every block redundantly reduces the 1056 bsums (L2-hot), subtracts mean.
__global__ __launch_bounds__(256) void k3_meansub(
    const float* __restrict__ bsums, float* __restrict__ outv, int n)
{
    __shared__ float red[256];
    const int tid = threadIdx.x;
    float s = 0.f;
    for (int i = tid; i < NTILE * B; i += 256) s += bsums[i];
    red[tid] = s;
    __syncthreads();
#pragma unroll
    for (int st = 128; st > 0; st >>= 1) {
        if (tid < st) red[tid] += red[tid + st];
        __syncthreads();
    }
    const float mean = red[0] / (float)(B * N1);
    __syncthreads();
    const int i = blockIdx.x * 256 + tid;
    if (i < n) outv[i] -= mean;
}

extern "C" void kernel_launch(void* const* d_in, const int* in_sizes, int n_in,
                              void* d_out, int out_size, void* d_ws, size_t ws_size,
                              hipStream_t stream)
{
    const float* sig = (const float*)d_in[0];
    const float* cd  = (const float*)d_in[1];
    // d_in[2] = index_diag (1 for these shapes)
    const float* w1  = (const float*)d_in[3];
    const float* b1  = (const float*)d_in[4];
    const float* w2  = (const float*)d_in[5];
    const float* b2  = (const float*)d_in[6];
    const float* wt  = (const float*)d_in[7];
    const float* bt  = (const float*)d_in[8];
    const float* w3  = (const float*)d_in[9];
    const float* b3  = (const float*)d_in[10];
    const float* cst = (const float*)d_in[11];

    float* outv = (float*)d_out;

    // workspace layout (floats)
    float* ws   = (float*)d_ws;
    float* wT   = ws;                  // CIN*32 = 4096
    float* bsum = wT + CIN * 32;       // NTILE*B = 1056

    k0_prep   <<<dim3(16), dim3(256), 0, stream>>>(w1, wT);
    k_main    <<<dim3(NTILE, B), dim3(256), 0, stream>>>(sig, wT, b1, w2, b2,
                                                         wt, bt, w3, b3, cd, cst, outv, bsum);
    k3_meansub<<<dim3((out_size + 255) / 256), dim3(256), 0, stream>>>(bsum, outv, out_size);
}